// Round 3
// baseline (329.414 us; speedup 1.0000x reference)
//
#include <hip/hip_runtime.h>
#include <cstdint>
#include <cstddef>

// Problem constants (match reference file)
#define BB 4
#define MM 8192
#define NN 6890
#define NSEG 128
#define SEGN 54           // ceil(6890/128); last segment has 32
#define CHUNKS 4          // MM / MQ
#define MQ 2048           // queries per nn block
#define QT 8              // queries per thread
#define NPAIR 4           // QT/2 packed-f32 pairs
#define TPB 256

typedef float v2f __attribute__((ext_vector_type(2)));

static constexpr float MIN_T2 = 0.005f * 0.005f;   // MIN_DIST_THRESH^2

// ws layout: [0, 262144) u64 packed[BB*MM] (d2_bits<<32 | idx), atomicMin.
// Initialized to 0xFF..FF (= u64 max = +inf sentinel) via hipMemsetAsync.

// Kernel 1: brute-force NN over one (batch, m-chunk, n-segment) per block.
// Hot loop is UNFILTERED min in shifted space e = s2 - 2 c.s (1.5 pk_fma +
// 1 cmp + 2 cndmask per pair). The min-dist filter is applied only in a rare
// fallback: if the unfiltered segment-min is < tmin, some candidate is
// too-close and we rescan this segment with the full filter (exec-masked,
// ~never taken). If the unfiltered min passes the filter, every candidate
// does, so filtered == unfiltered.
__global__ __launch_bounds__(TPB, 8) void nn_kernel(
    const float* __restrict__ cloth, const float* __restrict__ vt,
    const int* __restrict__ valid, unsigned long long* __restrict__ packed)
{
    __shared__ float4 lds[SEGN];
    int bid   = blockIdx.x;            // 2048 blocks
    int seg   = bid & (NSEG - 1);
    int chunk = (bid >> 7) & (CHUNKS - 1);
    int b     = bid >> 9;
    int n0    = seg * SEGN;
    int segn  = (NN - n0 < SEGN) ? (NN - n0) : SEGN;

    // fused candidate prep: (-2x,-2y,-2z, s2 or +inf if invalid)
    if (threadIdx.x < segn) {
        int n = n0 + threadIdx.x;
        const float* p = vt + ((size_t)b * NN + n) * 3;
        float x = p[0], y = p[1], z = p[2];
        float s2 = x * x + y * y + z * z;
        if (valid[b * NN + n] <= 0) s2 = __builtin_inff();
        lds[threadIdx.x] = make_float4(-2.0f * x, -2.0f * y, -2.0f * z, s2);
    }

    v2f qx[NPAIR], qy[NPAIR], qz[NPAIR], bd[NPAIR];
    float qc2[QT];
    int bi[QT];
    int m0 = chunk * MQ + threadIdx.x;
#pragma unroll
    for (int j = 0; j < QT; j++) {
        int m = m0 + j * TPB;
        const float* p = cloth + ((size_t)b * MM + m) * 3;
        float x = p[0], y = p[1], z = p[2];
        int pi = j >> 1;
        if (j & 1) { qx[pi].y = x; qy[pi].y = y; qz[pi].y = z;
                     bd[pi].y = __builtin_inff(); }
        else       { qx[pi].x = x; qy[pi].x = y; qz[pi].x = z;
                     bd[pi].x = __builtin_inff(); }
        qc2[j] = x * x + y * y + z * z;
        bi[j] = 0;
    }
    __syncthreads();

#pragma unroll 2
    for (int i = 0; i < segn; i++) {
        float4 c = lds[i];
        int n = n0 + i;
        v2f cx = {c.x, c.x}, cy = {c.y, c.y}, cz = {c.z, c.z}, cw = {c.w, c.w};
#pragma unroll
        for (int p = 0; p < NPAIR; p++) {
            // e = s2 - 2 c.s  (= d2 - qc2, order-preserving per query)
            v2f e = __builtin_elementwise_fma(cx, qx[p],
                    __builtin_elementwise_fma(cy, qy[p],
                    __builtin_elementwise_fma(cz, qz[p], cw)));
            bool ok0 = e.x < bd[p].x;
            bool ok1 = e.y < bd[p].y;
            bd[p].x = ok0 ? e.x : bd[p].x;
            bi[2*p]   = ok0 ? n : bi[2*p];
            bd[p].y = ok1 ? e.y : bd[p].y;
            bi[2*p+1] = ok1 ? n : bi[2*p+1];
        }
    }

    float bds[QT];
#pragma unroll
    for (int p = 0; p < NPAIR; p++) { bds[2*p] = bd[p].x; bds[2*p+1] = bd[p].y; }

    // rare fallback: unfiltered min is a too-close candidate -> rescan filtered
#pragma unroll
    for (int j = 0; j < QT; j++) {
        float tmin = MIN_T2 - qc2[j];
        if (bds[j] < tmin) {
            float qxj = (j & 1) ? qx[j >> 1].y : qx[j >> 1].x;
            float qyj = (j & 1) ? qy[j >> 1].y : qy[j >> 1].x;
            float qzj = (j & 1) ? qz[j >> 1].y : qz[j >> 1].x;
            float fb = __builtin_inff(); int fi = 0;
            for (int i = 0; i < segn; i++) {
                float4 c = lds[i];
                float e = fmaf(c.x, qxj, fmaf(c.y, qyj, fmaf(c.z, qzj, c.w)));
                bool ok = (e >= tmin) && (e < fb);
                fb = ok ? e : fb;
                fi = ok ? (n0 + i) : fi;
            }
            bds[j] = fb; bi[j] = fi;
        }
    }

#pragma unroll
    for (int j = 0; j < QT; j++) {
        int m = m0 + j * TPB;
        float d2 = bds[j] + qc2[j];                  // +inf stays +inf
        unsigned long long key =
            ((unsigned long long)__float_as_uint(d2) << 32) | (unsigned)bi[j];
        unsigned long long* p = &packed[(size_t)b * MM + m];
        // hint read: stale values are always >= truth (keys only decrease),
        // so skipping when key >= cur is safe; atomicMin is authoritative.
        unsigned long long cur = *p;
        if (key < cur) atomicMin(p, key);
    }
}

// Kernel 2: fused finalize + reduce. One block per batch (1024 threads),
// each thread handles 8 queries; block-reduce sum + match-any -> out[b].
__global__ __launch_bounds__(1024) void finalize_kernel(
    const unsigned long long* __restrict__ packed,
    const int* __restrict__ smpl_idx, const float* __restrict__ sdf,
    const int* __restrict__ cloth_idx, const float* __restrict__ sdf_thresh,
    const float* __restrict__ dist_thresh, float* __restrict__ out)
{
    int b = blockIdx.x;
    int ci0 = cloth_idx[0], ci1 = cloth_idx[1];
    float dt = dist_thresh[0], st = sdf_thresh[0];
    float sum = 0.0f; int mt = 0;
    for (int t = threadIdx.x; t < MM; t += 1024) {
        int q = b * MM + t;
        unsigned long long key = packed[q];
        float d2  = __uint_as_float((unsigned)(key >> 32));
        int   idx = (int)(unsigned)(key & 0xFFFFFFFFu);
        int target = smpl_idx[b * NN + idx];
        bool match = (target == ci0) || (target == ci1);
        bool near_ = sqrtf(d2) < dt;                 // inf -> false
        float s = sdf[q];
        sum += near_ ? (match ? fabsf(s) : fabsf(s - st)) : 0.0f;
        mt |= match ? 1 : 0;
    }
    for (int off = 32; off > 0; off >>= 1) {
        sum += __shfl_down(sum, off, 64);
        mt  |= __shfl_down(mt, off, 64);
    }
    __shared__ float wsum[16];
    __shared__ int   wmat[16];
    int wave = threadIdx.x >> 6;
    if ((threadIdx.x & 63) == 0) { wsum[wave] = sum; wmat[wave] = mt; }
    __syncthreads();
    if (threadIdx.x < 64) {
        float s2 = (threadIdx.x < 16) ? wsum[threadIdx.x] : 0.0f;
        int   m2 = (threadIdx.x < 16) ? wmat[threadIdx.x] : 0;
        for (int off = 8; off > 0; off >>= 1) {
            s2 += __shfl_down(s2, off, 64);
            m2 |= __shfl_down(m2, off, 64);
        }
        if (threadIdx.x == 0)
            out[b] = s2 * (1.0f / (float)MM) * (m2 ? 1.0f : 0.0f);
    }
}

extern "C" void kernel_launch(void* const* d_in, const int* in_sizes, int n_in,
                              void* d_out, int out_size, void* d_ws, size_t ws_size,
                              hipStream_t stream)
{
    const float* sdf         = (const float*)d_in[0];
    const float* cloth       = (const float*)d_in[1];
    const int*   smpl_idx    = (const int*)d_in[2];
    const int*   valid       = (const int*)d_in[3];
    const int*   cloth_idx   = (const int*)d_in[4];
    const float* sdf_thresh  = (const float*)d_in[5];
    const float* dist_thresh = (const float*)d_in[6];
    const float* vt          = (const float*)d_in[7];

    unsigned long long* packed = (unsigned long long*)d_ws;

    // 0xFF..FF == u64 max == (+inf, idx ~0) sentinel for the atomicMin array
    hipMemsetAsync(packed, 0xFF, (size_t)BB * MM * 8, stream);
    nn_kernel<<<BB * CHUNKS * NSEG, TPB, 0, stream>>>(cloth, vt, valid, packed);
    finalize_kernel<<<BB, 1024, 0, stream>>>(
        packed, smpl_idx, sdf, cloth_idx, sdf_thresh, dist_thresh, (float*)d_out);
}

// Round 4
// 328.539 us; speedup vs baseline: 1.0027x; 1.0027x over previous
//
#include <hip/hip_runtime.h>
#include <hip/hip_cooperative_groups.h>
#include <cstdint>
#include <cstddef>

namespace cg = cooperative_groups;

// Problem constants (match reference file)
#define BB 4
#define MM 8192
#define NN 6890
#define NSEG 32
#define SEGN 216          // ceil(6890/32); last segment has 194
#define CHUNKS 4          // MM / MQ
#define MQ 2048           // queries per block in phase 1
#define QT 8              // queries per thread
#define NPAIR 4           // QT/2 packed-f32 pairs
#define TPB 256
#define NBLK (BB * CHUNKS * NSEG)   // 512 blocks = 2/CU, co-resident
#define NQ (BB * MM)                 // 32768 queries

typedef float v2f __attribute__((ext_vector_type(2)));

static constexpr float MIN_T2 = 0.005f * 0.005f;   // MIN_DIST_THRESH^2

// ws layout (bytes):
//   [0, 8388608)           u64 partials[NSEG][NQ]  (d2_bits<<32 | idx)
//   [8388608, 8389120)     float bsum[128]
//   [8389120, 8389632)     int   bmatch[128]
#define OFF_BSUM   8388608
#define OFF_BMATCH 8389120

static __device__ __forceinline__ unsigned long long u64min(
    unsigned long long a, unsigned long long b) { return a < b ? a : b; }

// Single cooperative kernel, 3 phases separated by grid.sync():
//  P1: per-(batch, m-chunk, n-segment) NN -> plain coalesced partial writes
//      (NO atomics — R3 showed device-scope atomicMin ping-pongs across XCD
//       L2s: WRITE_SIZE 8->138 MB, VALUBusy 11%).
//  P2: per-query u64-min over 32 segment partials (tiebreak = lowest idx,
//      same as argmin), gather target, contribution, block-reduce -> 128 sums.
//  P3: block 0 reduces 128 -> 4 batch losses.
__global__ __launch_bounds__(TPB) void fused_kernel(
    const float* __restrict__ cloth, const float* __restrict__ vt,
    const int* __restrict__ valid, const int* __restrict__ smpl_idx,
    const float* __restrict__ sdf, const int* __restrict__ cloth_idx,
    const float* __restrict__ sdf_thresh, const float* __restrict__ dist_thresh,
    unsigned long long* __restrict__ partials, float* __restrict__ bsum,
    int* __restrict__ bmatch, float* __restrict__ out)
{
    cg::grid_group grid = cg::this_grid();
    __shared__ float4 lds[SEGN];
    __shared__ float wsum[4];
    __shared__ int   wmat[4];

    // ---------------- phase 1: segmented NN ----------------
    {
        int bid   = blockIdx.x;            // 512 blocks
        int seg   = bid & (NSEG - 1);
        int chunk = (bid >> 5) & (CHUNKS - 1);
        int b     = bid >> 7;
        int n0    = seg * SEGN;
        int segn  = (NN - n0 < SEGN) ? (NN - n0) : SEGN;

        // fused candidate prep: (-2x,-2y,-2z, s2 or +inf if invalid)
        if (threadIdx.x < segn) {
            int n = n0 + threadIdx.x;
            const float* p = vt + ((size_t)b * NN + n) * 3;
            float x = p[0], y = p[1], z = p[2];
            float s2 = x * x + y * y + z * z;
            if (valid[b * NN + n] <= 0) s2 = __builtin_inff();
            lds[threadIdx.x] = make_float4(-2.0f * x, -2.0f * y, -2.0f * z, s2);
        }

        v2f qx[NPAIR], qy[NPAIR], qz[NPAIR], bd[NPAIR];
        float qc2[QT];
        int bi[QT];
        int m0 = chunk * MQ + threadIdx.x;
#pragma unroll
        for (int j = 0; j < QT; j++) {
            int m = m0 + j * TPB;
            const float* p = cloth + ((size_t)b * MM + m) * 3;
            float x = p[0], y = p[1], z = p[2];
            int pi = j >> 1;
            if (j & 1) { qx[pi].y = x; qy[pi].y = y; qz[pi].y = z;
                         bd[pi].y = __builtin_inff(); }
            else       { qx[pi].x = x; qy[pi].x = y; qz[pi].x = z;
                         bd[pi].x = __builtin_inff(); }
            qc2[j] = x * x + y * y + z * z;
            bi[j] = 0;
        }
        __syncthreads();

        // Hot loop: UNFILTERED min in shifted space e = s2 - 2 c.s
        // (3 pk_fma + 2 cmp + 4 cndmask per float2-pair of queries).
#pragma unroll 2
        for (int i = 0; i < segn; i++) {
            float4 c = lds[i];
            int n = n0 + i;
            v2f cx = {c.x, c.x}, cy = {c.y, c.y}, cz = {c.z, c.z}, cw = {c.w, c.w};
#pragma unroll
            for (int p = 0; p < NPAIR; p++) {
                v2f e = __builtin_elementwise_fma(cx, qx[p],
                        __builtin_elementwise_fma(cy, qy[p],
                        __builtin_elementwise_fma(cz, qz[p], cw)));
                bool ok0 = e.x < bd[p].x;
                bool ok1 = e.y < bd[p].y;
                bd[p].x = ok0 ? e.x : bd[p].x;
                bi[2*p]   = ok0 ? n : bi[2*p];
                bd[p].y = ok1 ? e.y : bd[p].y;
                bi[2*p+1] = ok1 ? n : bi[2*p+1];
            }
        }

        float bds[QT];
#pragma unroll
        for (int p = 0; p < NPAIR; p++) { bds[2*p] = bd[p].x; bds[2*p+1] = bd[p].y; }

        // rare fallback: unfiltered min is a too-close candidate -> rescan
        // this segment with the full filter (if min passes, all do).
#pragma unroll
        for (int j = 0; j < QT; j++) {
            float tmin = MIN_T2 - qc2[j];
            if (bds[j] < tmin) {
                float qxj = (j & 1) ? qx[j >> 1].y : qx[j >> 1].x;
                float qyj = (j & 1) ? qy[j >> 1].y : qy[j >> 1].x;
                float qzj = (j & 1) ? qz[j >> 1].y : qz[j >> 1].x;
                float fb = __builtin_inff(); int fi = 0;
                for (int i = 0; i < segn; i++) {
                    float4 c = lds[i];
                    float e = fmaf(c.x, qxj, fmaf(c.y, qyj, fmaf(c.z, qzj, c.w)));
                    bool ok = (e >= tmin) && (e < fb);
                    fb = ok ? e : fb;
                    fi = ok ? (n0 + i) : fi;
                }
                bds[j] = fb; bi[j] = fi;
            }
        }

        // coalesced partial write: d2 = e + qc2 >= MIN_T2 > 0 (or +inf), so
        // float bits order correctly as unsigned.
#pragma unroll
        for (int j = 0; j < QT; j++) {
            int q = b * MM + m0 + j * TPB;
            float d2 = bds[j] + qc2[j];
            unsigned long long key =
                ((unsigned long long)__float_as_uint(d2) << 32) | (unsigned)bi[j];
            partials[(size_t)seg * NQ + q] = key;
        }
    }

    __threadfence();
    grid.sync();

    // ---------------- phase 2: reduce segments + finalize ----------------
    if (blockIdx.x < NQ / TPB) {           // 128 blocks, 1 query/thread
        int q = blockIdx.x * TPB + threadIdx.x;
        int b = q >> 13;
        unsigned long long m0 = ~0ULL, m1 = ~0ULL, m2 = ~0ULL, m3 = ~0ULL;
#pragma unroll
        for (int s = 0; s < NSEG; s += 4) {
            m0 = u64min(m0, partials[(size_t)(s + 0) * NQ + q]);
            m1 = u64min(m1, partials[(size_t)(s + 1) * NQ + q]);
            m2 = u64min(m2, partials[(size_t)(s + 2) * NQ + q]);
            m3 = u64min(m3, partials[(size_t)(s + 3) * NQ + q]);
        }
        unsigned long long key = u64min(u64min(m0, m1), u64min(m2, m3));

        float d2  = __uint_as_float((unsigned)(key >> 32));
        int   idx = (int)(unsigned)(key & 0xFFFFFFFFu);
        int target = smpl_idx[b * NN + idx];
        int ci0 = cloth_idx[0], ci1 = cloth_idx[1];
        bool match = (target == ci0) || (target == ci1);
        bool near_ = sqrtf(d2) < dist_thresh[0];     // inf -> false
        float s = sdf[q];
        float contrib = near_ ? (match ? fabsf(s) : fabsf(s - sdf_thresh[0]))
                              : 0.0f;
        int mt = match ? 1 : 0;

        for (int off = 32; off > 0; off >>= 1) {
            contrib += __shfl_down(contrib, off, 64);
            mt      |= __shfl_down(mt, off, 64);
        }
        int wave = threadIdx.x >> 6;
        if ((threadIdx.x & 63) == 0) { wsum[wave] = contrib; wmat[wave] = mt; }
        __syncthreads();
        if (threadIdx.x == 0) {
            bsum[blockIdx.x]   = wsum[0] + wsum[1] + wsum[2] + wsum[3];
            bmatch[blockIdx.x] = wmat[0] | wmat[1] | wmat[2] | wmat[3];
        }
    }

    __threadfence();
    grid.sync();

    // ---------------- phase 3: 128 -> 4 batch losses ----------------
    if (blockIdx.x == 0 && threadIdx.x < 128) {
        int t = threadIdx.x;                 // batch = t>>5, 32 entries each
        float s = bsum[t];
        int   m = bmatch[t];
        for (int off = 16; off > 0; off >>= 1) {
            s += __shfl_down(s, off, 32);    // 32-wide subgroups
            m |= __shfl_down(m, off, 32);
        }
        if ((t & 31) == 0)
            out[t >> 5] = s * (1.0f / (float)MM) * (m ? 1.0f : 0.0f);
    }
}

extern "C" void kernel_launch(void* const* d_in, const int* in_sizes, int n_in,
                              void* d_out, int out_size, void* d_ws, size_t ws_size,
                              hipStream_t stream)
{
    const float* sdf         = (const float*)d_in[0];
    const float* cloth       = (const float*)d_in[1];
    const int*   smpl_idx    = (const int*)d_in[2];
    const int*   valid       = (const int*)d_in[3];
    const int*   cloth_idx   = (const int*)d_in[4];
    const float* sdf_thresh  = (const float*)d_in[5];
    const float* dist_thresh = (const float*)d_in[6];
    const float* vt          = (const float*)d_in[7];

    char* ws = (char*)d_ws;
    unsigned long long* partials = (unsigned long long*)ws;
    float* bsum   = (float*)(ws + OFF_BSUM);
    int*   bmatch = (int*)(ws + OFF_BMATCH);
    float* outp   = (float*)d_out;

    void* args[] = { &cloth, &vt, &valid, &smpl_idx, &sdf, &cloth_idx,
                     &sdf_thresh, &dist_thresh, &partials, &bsum, &bmatch,
                     &outp };
    hipLaunchCooperativeKernel(reinterpret_cast<void*>(fused_kernel),
                               dim3(NBLK), dim3(TPB), args, 0, stream);
}

// Round 5
// 116.166 us; speedup vs baseline: 2.8357x; 2.8282x over previous
//
#include <hip/hip_runtime.h>
#include <cstdint>
#include <cstddef>

// Problem constants (match reference file)
#define BB 4
#define MM 8192
#define NN 6890
#define NSEG 128
#define SEGN 54           // ceil(6890/128); last segment has 32
#define CHUNKS 4          // MM / MQ
#define MQ 2048           // queries per nn block
#define QT 8              // queries per thread
#define NPAIR 4           // QT/2 packed-f32 pairs
#define TPB 256
#define NQ (BB * MM)      // 32768 queries

typedef float v2f __attribute__((ext_vector_type(2)));

static constexpr float MIN_T2 = 0.005f * 0.005f;   // MIN_DIST_THRESH^2

// ws layout (bytes):
//   [0, 33554432)            u64 partials[NSEG][NQ]  (d2_bits<<32 | idx)
//   [33554432, 33555456)     float bsum[256]
//   [33555456, 33556480)     int   bmatch[256]
#define OFF_BSUM   33554432
#define OFF_BMATCH 33555456

static __device__ __forceinline__ unsigned long long u64min(
    unsigned long long a, unsigned long long b) { return a < b ? a : b; }

// Kernel 1: per-(batch, m-chunk, n-segment) NN. NO atomics (R3: device-scope
// atomicMin ping-pongs lines across XCD L2s -> 200 MB coherence traffic),
// NO grid.sync (R4: 512-block spin barrier costs ~100us each). Each block
// writes its partial min as a plain coalesced u64 store to a unique slot.
__global__ __launch_bounds__(TPB) void nn_kernel(
    const float* __restrict__ cloth, const float* __restrict__ vt,
    const int* __restrict__ valid, unsigned long long* __restrict__ partials)
{
    __shared__ float4 lds[SEGN];
    int bid   = blockIdx.x;            // 2048 blocks = 8/CU
    int seg   = bid & (NSEG - 1);
    int chunk = (bid >> 7) & (CHUNKS - 1);
    int b     = bid >> 9;
    int n0    = seg * SEGN;
    int segn  = (NN - n0 < SEGN) ? (NN - n0) : SEGN;

    // fused candidate prep: (-2x,-2y,-2z, s2 or +inf if invalid)
    if (threadIdx.x < segn) {
        int n = n0 + threadIdx.x;
        const float* p = vt + ((size_t)b * NN + n) * 3;
        float x = p[0], y = p[1], z = p[2];
        float s2 = x * x + y * y + z * z;
        if (valid[b * NN + n] <= 0) s2 = __builtin_inff();
        lds[threadIdx.x] = make_float4(-2.0f * x, -2.0f * y, -2.0f * z, s2);
    }

    v2f qx[NPAIR], qy[NPAIR], qz[NPAIR], bd[NPAIR];
    float qc2[QT];
    int bi[QT];
    int m0 = chunk * MQ + threadIdx.x;
#pragma unroll
    for (int j = 0; j < QT; j++) {
        int m = m0 + j * TPB;
        const float* p = cloth + ((size_t)b * MM + m) * 3;
        float x = p[0], y = p[1], z = p[2];
        int pi = j >> 1;
        if (j & 1) { qx[pi].y = x; qy[pi].y = y; qz[pi].y = z;
                     bd[pi].y = __builtin_inff(); }
        else       { qx[pi].x = x; qy[pi].x = y; qz[pi].x = z;
                     bd[pi].x = __builtin_inff(); }
        qc2[j] = x * x + y * y + z * z;
        bi[j] = 0;
    }
    __syncthreads();

    // Hot loop: UNFILTERED min in shifted space e = s2 - 2 c.s
    // (3 pk_fma + 2 cmp + 4 cndmask per float2-pair of queries).
#pragma unroll 2
    for (int i = 0; i < segn; i++) {
        float4 c = lds[i];
        int n = n0 + i;
        v2f cx = {c.x, c.x}, cy = {c.y, c.y}, cz = {c.z, c.z}, cw = {c.w, c.w};
#pragma unroll
        for (int p = 0; p < NPAIR; p++) {
            v2f e = __builtin_elementwise_fma(cx, qx[p],
                    __builtin_elementwise_fma(cy, qy[p],
                    __builtin_elementwise_fma(cz, qz[p], cw)));
            bool ok0 = e.x < bd[p].x;
            bool ok1 = e.y < bd[p].y;
            bd[p].x = ok0 ? e.x : bd[p].x;
            bi[2*p]   = ok0 ? n : bi[2*p];
            bd[p].y = ok1 ? e.y : bd[p].y;
            bi[2*p+1] = ok1 ? n : bi[2*p+1];
        }
    }

    float bds[QT];
#pragma unroll
    for (int p = 0; p < NPAIR; p++) { bds[2*p] = bd[p].x; bds[2*p+1] = bd[p].y; }

    // rare fallback: unfiltered min is a too-close candidate -> rescan this
    // segment with the full filter (if the min passes, all candidates do).
#pragma unroll
    for (int j = 0; j < QT; j++) {
        float tmin = MIN_T2 - qc2[j];
        if (bds[j] < tmin) {
            float qxj = (j & 1) ? qx[j >> 1].y : qx[j >> 1].x;
            float qyj = (j & 1) ? qy[j >> 1].y : qy[j >> 1].x;
            float qzj = (j & 1) ? qz[j >> 1].y : qz[j >> 1].x;
            float fb = __builtin_inff(); int fi = 0;
            for (int i = 0; i < segn; i++) {
                float4 c = lds[i];
                float e = fmaf(c.x, qxj, fmaf(c.y, qyj, fmaf(c.z, qzj, c.w)));
                bool ok = (e >= tmin) && (e < fb);
                fb = ok ? e : fb;
                fi = ok ? (n0 + i) : fi;
            }
            bds[j] = fb; bi[j] = fi;
        }
    }

    // coalesced partial store: d2 = e + qc2 >= MIN_T2 > 0 (or +inf), so
    // float bits order correctly as unsigned; low 32 bits = idx tiebreak.
#pragma unroll
    for (int j = 0; j < QT; j++) {
        int q = b * MM + m0 + j * TPB;
        float d2 = bds[j] + qc2[j];
        unsigned long long key =
            ((unsigned long long)__float_as_uint(d2) << 32) | (unsigned)bi[j];
        partials[(size_t)seg * NQ + q] = key;
    }
}

// Kernel 2: per-query u64-min over NSEG segment partials (exact argmin with
// lowest-index tiebreak), gather target, contribution, block-reduce.
__global__ __launch_bounds__(128) void finalize_kernel(
    const unsigned long long* __restrict__ partials,
    const int* __restrict__ smpl_idx, const float* __restrict__ sdf,
    const int* __restrict__ cloth_idx, const float* __restrict__ sdf_thresh,
    const float* __restrict__ dist_thresh,
    float* __restrict__ bsum, int* __restrict__ bmatch)
{
    int q = blockIdx.x * 128 + threadIdx.x;   // 256 blocks x 128 = NQ
    int b = q >> 13;
    unsigned long long m0 = ~0ULL, m1 = ~0ULL, m2 = ~0ULL, m3 = ~0ULL;
#pragma unroll 4
    for (int s = 0; s < NSEG; s += 4) {
        m0 = u64min(m0, partials[(size_t)(s + 0) * NQ + q]);
        m1 = u64min(m1, partials[(size_t)(s + 1) * NQ + q]);
        m2 = u64min(m2, partials[(size_t)(s + 2) * NQ + q]);
        m3 = u64min(m3, partials[(size_t)(s + 3) * NQ + q]);
    }
    unsigned long long key = u64min(u64min(m0, m1), u64min(m2, m3));

    float d2  = __uint_as_float((unsigned)(key >> 32));
    int   idx = (int)(unsigned)(key & 0xFFFFFFFFu);
    int target = smpl_idx[b * NN + idx];
    int ci0 = cloth_idx[0], ci1 = cloth_idx[1];
    bool match = (target == ci0) || (target == ci1);
    bool near_ = sqrtf(d2) < dist_thresh[0];     // inf -> false
    float s = sdf[q];
    float contrib = near_ ? (match ? fabsf(s) : fabsf(s - sdf_thresh[0])) : 0.0f;
    int mt = match ? 1 : 0;

    for (int off = 32; off > 0; off >>= 1) {
        contrib += __shfl_down(contrib, off, 64);
        mt      |= __shfl_down(mt, off, 64);
    }
    __shared__ float wsum[2];
    __shared__ int   wmat[2];
    int wave = threadIdx.x >> 6;
    if ((threadIdx.x & 63) == 0) { wsum[wave] = contrib; wmat[wave] = mt; }
    __syncthreads();
    if (threadIdx.x == 0) {
        bsum[blockIdx.x]   = wsum[0] + wsum[1];
        bmatch[blockIdx.x] = wmat[0] | wmat[1];
    }
}

// Kernel 3: 256 block-partials -> 4 batch losses (64 partials per batch,
// one wave per batch).
__global__ __launch_bounds__(256) void reduce_kernel(
    const float* __restrict__ bs, const int* __restrict__ bm,
    float* __restrict__ out)
{
    int t = threadIdx.x;          // batch = t>>6
    float s = bs[t];
    int   m = bm[t];
    for (int off = 32; off > 0; off >>= 1) {
        s += __shfl_down(s, off, 64);
        m |= __shfl_down(m, off, 64);
    }
    if ((t & 63) == 0)
        out[t >> 6] = s * (1.0f / (float)MM) * (m ? 1.0f : 0.0f);
}

extern "C" void kernel_launch(void* const* d_in, const int* in_sizes, int n_in,
                              void* d_out, int out_size, void* d_ws, size_t ws_size,
                              hipStream_t stream)
{
    const float* sdf         = (const float*)d_in[0];
    const float* cloth       = (const float*)d_in[1];
    const int*   smpl_idx    = (const int*)d_in[2];
    const int*   valid       = (const int*)d_in[3];
    const int*   cloth_idx   = (const int*)d_in[4];
    const float* sdf_thresh  = (const float*)d_in[5];
    const float* dist_thresh = (const float*)d_in[6];
    const float* vt          = (const float*)d_in[7];

    char* ws = (char*)d_ws;
    unsigned long long* partials = (unsigned long long*)ws;
    float* bsum   = (float*)(ws + OFF_BSUM);
    int*   bmatch = (int*)(ws + OFF_BMATCH);

    nn_kernel<<<BB * CHUNKS * NSEG, TPB, 0, stream>>>(cloth, vt, valid, partials);
    finalize_kernel<<<NQ / 128, 128, 0, stream>>>(
        partials, smpl_idx, sdf, cloth_idx, sdf_thresh, dist_thresh,
        bsum, bmatch);
    reduce_kernel<<<1, 256, 0, stream>>>(bsum, bmatch, (float*)d_out);
}